// Round 20
// baseline (256.054 us; speedup 1.0000x reference)
//
#include <hip/hip_runtime.h>
#include <stdint.h>

#define BATCH 8192
#define H1 28
#define W1 28
#define C1 16
#define P1 14
#define C2 32
#define P2 7

#define NPIX1  (BATCH*H1*W1)    // 6,422,528
#define NPOOL1 (BATCH*P1*P1)    // 1,605,632
#define NPOOL2 (BATCH*P2*P2)    // 401,408

#define QD_BLOCKS 3136          // 401,408 quads, 128/block (2 wave-pairs)
#define S1_BLOCKS 1568          // sign1: NPOOL1/(256*4)
#define C2F_BLOCKS 3136         // conv2 v3: 128 positions/block, 2/thread
#define SF_IMGS   16
#define SF_BLOCKS 512           // BATCH/SF_IMGS

typedef float f32x2 __attribute__((ext_vector_type(2)));
typedef float f32x4 __attribute__((ext_vector_type(4)));
typedef short s16x4 __attribute__((ext_vector_type(4)));
typedef short s16x8 __attribute__((ext_vector_type(8)));

// ---------------------------------------------------------------------------
// Weight prep, parallelized across 13 blocks (round-15 proven).
// ---------------------------------------------------------------------------
__global__ __launch_bounds__(256) void k_prep(const float* __restrict__ w1,
                                              const float* __restrict__ w2,
                                              const float* __restrict__ fcw,
                                              const float* __restrict__ g1,
                                              const float* __restrict__ g2,
                                              unsigned* __restrict__ w1s,
                                              unsigned* __restrict__ w2p,
                                              unsigned short* __restrict__ w2k,
                                              unsigned* __restrict__ fcp,
                                              unsigned* __restrict__ selb) {
    const int blk = blockIdx.x;
    if (blk == 0) {
        for (int c = threadIdx.x; c < 16; c += 256) {
            unsigned sb = 0;
            for (int i = 0; i < 25; ++i)
                if (w1[c*25 + i] < 0.f) sb |= 1u << i;
            w1s[c] = sb;
        }
        if (threadIdx.x == 0) {
            unsigned s1 = 0, s2 = 0;
            for (int c = 0; c < 16; ++c) if (g1[c] < 0.f) s1 |= 1u << c;
            for (int c = 0; c < 32; ++c) if (g2[c] < 0.f) s2 |= 1u << c;
            selb[0] = s1; selb[1] = s2;
        }
    } else if (blk == 1) {
        for (int i = threadIdx.x; i < 32*13; i += 256) {
            int co = i / 13, j = i % 13;
            int k1, k2;
            if (j < 10)      { k1 = (j/2)*5 + (j&1)*2; k2 = k1 + 1; }
            else if (j == 10){ k1 = 4;  k2 = 9;  }
            else if (j == 11){ k1 = 14; k2 = 19; }
            else             { k1 = 24; k2 = -1; }
            unsigned lo = 0, hi = 0;
            for (int ci = 0; ci < 16; ++ci) {
                if (w2[co*400 + ci*25 + k1] >= 0.f) lo |= 1u << ci;
                if (k2 >= 0 && w2[co*400 + ci*25 + k2] >= 0.f) hi |= 1u << ci;
            }
            w2p[i] = lo | (hi << 16);
        }
    } else if (blk == 2) {
        __shared__ unsigned short sw2b[800];
        for (int i = threadIdx.x; i < 800; i += 256) {
            int co = i / 25, kk = i % 25;
            unsigned m = 0;
            for (int ci = 0; ci < 16; ++ci)
                if (w2[co*400 + ci*25 + kk] >= 0.f) m |= 1u << ci;
            sw2b[i] = (unsigned short)m;
        }
        __syncthreads();
        const int lo5[5] = {2,1,0,0,0};
        const int hi5[5] = {4,4,4,3,2};
        for (int i = threadIdx.x; i < 800; i += 256) {
            int cls = i >> 5, co = i & 31;
            int rc = cls / 5, cc = cls % 5;
            int rlo = lo5[rc], rhi = hi5[rc], clo = lo5[cc], chi = hi5[cc];
            int C = 0;
            for (int ky = 0; ky < 5; ++ky)
                for (int kx = 0; kx < 5; ++kx)
                    if (ky < rlo || ky > rhi || kx < clo || kx > chi)
                        C += __popc((unsigned)sw2b[co*25 + ky*5 + kx]);
            int nv = (rhi - rlo + 1) * (chi - clo + 1);
            w2k[i] = (unsigned short)(16*nv + 2*C);
        }
    } else {
        int i0 = (blk - 3) * 392;
        for (int ii = threadIdx.x; ii < 392; ii += 256) {
            int i = i0 + ii;
            int j = i / 392, g = i % 392;
            unsigned v = 0;
            for (int by = 0; by < 4; ++by) {
                int k = g*4 + by;
                unsigned char s = (fcw[j*1568 + k] >= 0.f) ? 0x01 : 0xFF;
                v |= ((unsigned)s) << (8*by);
            }
            fcp[i] = v;
        }
    }
}

// ---------------------------------------------------------------------------
// conv1 QUAD (round-18 proven, single launch restored). Conflict-free
// LDS-transpose stats reduction (sqred pad 136).
// ---------------------------------------------------------------------------
__global__ __launch_bounds__(256) void k_conv1_quad(const float* __restrict__ x,
                                                    const unsigned* __restrict__ w1s,
                                                    const float* __restrict__ b1,
                                                    const unsigned* __restrict__ selb,
                                                    float* __restrict__ ext1,
                                                    double* __restrict__ partial1) {
    const int wave = threadIdx.x >> 6, lane = threadIdx.x & 63;
    const int half = wave & 1;
    const int pg   = wave >> 1;
    const int c0   = half << 3;
    const int elem = pg*64 + lane;      // 0..127 slot within channel-half
    unsigned selbs = __builtin_amdgcn_readfirstlane(selb[0]);

    __shared__ float sqred[2][16][136]; // pad 136 -> conflict-free both phases
    __shared__ float slb[2][16][8];

    float bv[8];
#pragma unroll
    for (int cl = 0; cl < 8; ++cl) bv[cl] = b1[c0 + cl];

    const int qq = blockIdx.x*128 + pg*64 + lane;
    const int b  = qq / 49;
    const int rr = qq % 49;
    const int qy = rr / 7, qx = rr % 7;
    const float* xb = x + (size_t)b * (H1*W1);

    const int ix0 = 4*qx - 2;
    const bool cL = (qx == 0), cR = (qx == 6);
    const int o0 = cL ? 0 : ix0;
    const int o3 = cR ? 24 : ix0 + 6;

    float xd[64];
#pragma unroll
    for (int dy = 0; dy < 8; ++dy) {
        int iy = 4*qy + dy - 2;
        bool rv = (iy >= 0) && (iy < H1);
        const float* rp = xb + (rv ? iy : 0)*W1;
        f32x2 p0 = *(const f32x2*)(rp + o0);
        f32x2 p1 = *(const f32x2*)(rp + ix0 + 2);
        f32x2 p2 = *(const f32x2*)(rp + ix0 + 4);
        f32x2 p3 = *(const f32x2*)(rp + o3);
        bool vL = rv && !cL, vR = rv && !cR;
        xd[dy*8+0] = vL ? p0.x : 0.f;
        xd[dy*8+1] = vL ? p0.y : 0.f;
        xd[dy*8+2] = rv ? p1.x : 0.f;
        xd[dy*8+3] = rv ? p1.y : 0.f;
        xd[dy*8+4] = rv ? p2.x : 0.f;
        xd[dy*8+5] = rv ? p2.y : 0.f;
        xd[dy*8+6] = vR ? p3.x : 0.f;
        xd[dy*8+7] = vR ? p3.y : 0.f;
    }

#pragma unroll
    for (int cl = 0; cl < 8; ++cl) {
        unsigned sb = __builtin_amdgcn_readfirstlane(w1s[c0 + cl]);
        f32x2 y00={0.f,0.f}, y01={0.f,0.f}, y10={0.f,0.f}, y11={0.f,0.f};
        f32x2 y20={0.f,0.f}, y21={0.f,0.f}, y30={0.f,0.f}, y31={0.f,0.f};
#pragma unroll
        for (int ky = 0; ky < 5; ++ky) {
#pragma unroll
            for (int kx = 0; kx < 5; ++kx) {
                float m = __uint_as_float(0x3F800000u ^
                            (((sb >> (ky*5 + kx)) & 1u) << 31));
                f32x2 mm = {m, m};
                f32x2 a0 = { xd[(0+ky)*8 + kx    ], xd[(0+ky)*8 + kx + 1] };
                f32x2 a1 = { xd[(0+ky)*8 + kx + 2], xd[(0+ky)*8 + kx + 3] };
                f32x2 b0 = { xd[(1+ky)*8 + kx    ], xd[(1+ky)*8 + kx + 1] };
                f32x2 b1v= { xd[(1+ky)*8 + kx + 2], xd[(1+ky)*8 + kx + 3] };
                f32x2 c0v= { xd[(2+ky)*8 + kx    ], xd[(2+ky)*8 + kx + 1] };
                f32x2 c1 = { xd[(2+ky)*8 + kx + 2], xd[(2+ky)*8 + kx + 3] };
                f32x2 d0 = { xd[(3+ky)*8 + kx    ], xd[(3+ky)*8 + kx + 1] };
                f32x2 d1 = { xd[(3+ky)*8 + kx + 2], xd[(3+ky)*8 + kx + 3] };
                y00 = a0*mm + y00;  y01 = a1*mm + y01;   // exact ±x adds
                y10 = b0*mm + y10;  y11 = b1v*mm + y11;
                y20 = c0v*mm + y20; y21 = c1*mm + y21;
                y30 = d0*mm + y30;  y31 = d1*mm + y31;
            }
        }
        float bb = bv[cl];
        f32x2 bb2 = {bb, bb};
        y00 += bb2; y01 += bb2; y10 += bb2; y11 += bb2;
        y20 += bb2; y21 += bb2; y30 += bb2; y31 += bb2;

        int c = c0 + cl;
        int sel = (selbs >> c) & 1;
        float e00 = sel ? fminf(fminf(y00.x,y00.y), fminf(y10.x,y10.y))
                        : fmaxf(fmaxf(y00.x,y00.y), fmaxf(y10.x,y10.y));
        float e01 = sel ? fminf(fminf(y01.x,y01.y), fminf(y11.x,y11.y))
                        : fmaxf(fmaxf(y01.x,y01.y), fmaxf(y11.x,y11.y));
        float e10 = sel ? fminf(fminf(y20.x,y20.y), fminf(y30.x,y30.y))
                        : fmaxf(fmaxf(y20.x,y20.y), fmaxf(y30.x,y30.y));
        float e11 = sel ? fminf(fminf(y21.x,y21.y), fminf(y31.x,y31.y))
                        : fmaxf(fmaxf(y21.x,y21.y), fmaxf(y31.x,y31.y));
        size_t base = (size_t)c*NPOOL1 + (size_t)b*(P1*P1) + (2*qy)*P1 + 2*qx;
        f32x2 ev0 = {e00, e01};
        f32x2 ev1 = {e10, e11};
        *(f32x2*)(ext1 + base)      = ev0;
        *(f32x2*)(ext1 + base + P1) = ev1;

        f32x2 sp = ((y00 + y01) + (y10 + y11)) + ((y20 + y21) + (y30 + y31));
        f32x2 qp = y00*y00;
        qp = y01*y01 + qp; qp = y10*y10 + qp; qp = y11*y11 + qp;
        qp = y20*y20 + qp; qp = y21*y21 + qp; qp = y30*y30 + qp;
        qp = y31*y31 + qp;
        sqred[0][c][elem] = sp.x + sp.y;
        sqred[1][c][elem] = qp.x + qp.y;
    }

    __syncthreads();
    {
        int w = threadIdx.x;
        int c = w >> 4, sub = w & 15, typ = sub >> 3, m = sub & 7;
        float acc = 0.f;
#pragma unroll
        for (int k = 0; k < 16; ++k) acc += sqred[typ][c][k*8 + m];
        slb[typ][c][m] = acc;
    }
    __syncthreads();
    if (threadIdx.x < 32) {
        int c = threadIdx.x & 15, typ = threadIdx.x >> 4;
        double d = 0.0;
#pragma unroll
        for (int j = 0; j < 8; ++j) d += (double)slb[typ][c][j];
        partial1[(size_t)blockIdx.x*32 + typ*16 + c] = d;
    }
}

// finalize1: reduce partials, per-channel threshold + mode
__global__ __launch_bounds__(256) void k_finalize1(const double* __restrict__ part,
                                                   int nblk,
                                                   const float* __restrict__ g,
                                                   const float* __restrict__ be,
                                                   double* __restrict__ thr,
                                                   int* __restrict__ mode) {
    int c = blockIdx.x;
    double s = 0, q = 0;
    for (int i = threadIdx.x; i < nblk; i += 256) {
        s += part[(size_t)i*32 + c];
        q += part[(size_t)i*32 + 16 + c];
    }
    __shared__ double ls[256], lq[256];
    ls[threadIdx.x] = s; lq[threadIdx.x] = q;
    __syncthreads();
    for (int st = 128; st > 0; st >>= 1) {
        if (threadIdx.x < st) {
            ls[threadIdx.x] += ls[threadIdx.x + st];
            lq[threadIdx.x] += lq[threadIdx.x + st];
        }
        __syncthreads();
    }
    if (threadIdx.x == 0) {
        double N = (double)NPIX1;
        double m = ls[0] / N;
        double var = lq[0] / N - m*m;
        double gamma = (double)g[c], beta = (double)be[c];
        double sc = gamma / sqrt(var + 1e-5);
        int md; double tt = 0.0;
        if (sc > 0)      { md = 0; tt = m - beta / sc; }
        else if (sc < 0) { md = 1; tt = m - beta / sc; }
        else             { md = (beta >= 0) ? 2 : 3; }
        thr[c] = tt; mode[c] = md;
    }
}

// sign1 x4 (round-19): 4 positions/thread, vectorized loads/stores.
__global__ __launch_bounds__(256) void k_sign1(const float* __restrict__ ext1,
                                               const double* __restrict__ thr,
                                               const int* __restrict__ mode,
                                               unsigned short* __restrict__ a1b) {
    int t0 = (blockIdx.x*256 + threadIdx.x) * 4;
    unsigned bits0 = 0, bits1 = 0, bits2 = 0, bits3 = 0;
#pragma unroll
    for (int c = 0; c < 16; ++c) {
        f32x4 v = *(const f32x4*)(ext1 + (size_t)c*NPOOL1 + t0);
        int md = mode[c]; double tt = thr[c];
        bool p0, p1, p2, p3;
        if (md == 0) {
            p0 = ((double)v.x >= tt); p1 = ((double)v.y >= tt);
            p2 = ((double)v.z >= tt); p3 = ((double)v.w >= tt);
        } else if (md == 1) {
            p0 = ((double)v.x <= tt); p1 = ((double)v.y <= tt);
            p2 = ((double)v.z <= tt); p3 = ((double)v.w <= tt);
        } else {
            bool pv = (md == 2);
            p0 = pv; p1 = pv; p2 = pv; p3 = pv;
        }
        bits0 |= (p0 ? 1u : 0u) << c;
        bits1 |= (p1 ? 1u : 0u) << c;
        bits2 |= (p2 ? 1u : 0u) << c;
        bits3 |= (p3 ? 1u : 0u) << c;
    }
    s16x4 outv = { (short)bits0, (short)bits1, (short)bits2, (short)bits3 };
    *(s16x4*)(a1b + t0) = outv;
}

// ---------------------------------------------------------------------------
// conv2 fused v3: 2 pooled positions per thread (128/block, halves waves;
// staging/barrier amortized 2x), LDS word-reads + funnel-shift packing,
// coalesced ext2 [t][32], and LDS-transpose stats reduction (pad 67:
// writer exactly 2-way bank-free) replacing the 128-op shuffle butterfly.
// s,q accumulate across both positions (exact integers; order-free).
// ---------------------------------------------------------------------------
__global__ __launch_bounds__(256) void k_conv2_fused(const unsigned short* __restrict__ a1b,
                                                     const unsigned* __restrict__ w2p,
                                                     const unsigned short* __restrict__ w2k,
                                                     const unsigned* __restrict__ selb,
                                                     short* __restrict__ ext2,
                                                     int* __restrict__ partial2) {
    __shared__ unsigned short raw[4*18*18];
    __shared__ unsigned sw[32*13];
    __shared__ unsigned short kt[25*32];
    __shared__ int sqr[2][32][67];
    __shared__ int slb[2][32][4];

    const int B0 = blockIdx.x * 128;
    const int i0 = B0 / 49;
    const int ilast = (B0 + 127) / 49;
    const int icnt = ilast - i0 + 1;       // 3 or 4

    for (int i = threadIdx.x; i < 416; i += 256) sw[i] = w2p[i];
    for (int i = threadIdx.x; i < 800; i += 256) kt[i] = w2k[i];
    {
        unsigned* rz = (unsigned*)raw;
        int n32 = icnt * 162;
        for (int i = threadIdx.x; i < n32; i += 256) rz[i] = 0u;
    }
    __syncthreads();
    {
        int n = icnt * 196;
        for (int e = threadIdx.x; e < n; e += 256) {
            int img = e / 196, lin = e % 196;
            unsigned short v = a1b[(size_t)(i0 + img)*196 + lin];
            int py = lin / 14, px = lin % 14;
            raw[(img*18 + py + 2)*18 + px + 2] = v;
        }
    }
    __syncthreads();

    const int quarter = threadIdx.x & 3;
    const int c0 = quarter << 3;
    const int pslot = threadIdx.x >> 2;    // 0..63
    const unsigned selbs = __builtin_amdgcn_readfirstlane(selb[1]);
    const unsigned* raw32 = (const unsigned*)raw;

    int s[8], q[8];
#pragma unroll
    for (int i = 0; i < 8; ++i) { s[i] = 0; q[i] = 0; }

#pragma unroll
    for (int pos = 0; pos < 2; ++pos) {
        const int t = B0 + pos*64 + pslot;
        const int img = t / 49 - i0;
        const int r = t % 49;
        const int qy = r / 7, qx = r % 7;

        unsigned aw[6][3];
#pragma unroll
        for (int wy = 0; wy < 6; ++wy) {
            int base16 = (img*18 + 2*qy + wy)*18 + 2*qx;   // even
            int wbase = base16 >> 1;
            aw[wy][0] = raw32[wbase + 0];
            aw[wy][1] = raw32[wbase + 1];
            aw[wy][2] = raw32[wbase + 2];
        }

        int mx[8], mn[8];
#pragma unroll
        for (int i = 0; i < 8; ++i) { mx[i] = -1000000; mn[i] = 1000000; }

#pragma unroll
        for (int sp = 0; sp < 4; ++sp) {
            const int sy = sp >> 1, sx = sp & 1;
            const int oy = 2*qy + sy, ox = 2*qx + sx;
            const int rcls = (oy < 2) ? oy : ((oy > 11) ? oy - 9 : 2);
            const int ccls = (ox < 2) ? ox : ((ox > 11) ? ox - 9 : 2);
            const int kbase = (rcls*5 + ccls) * 32 + c0;

            unsigned ap[13];
            if (sx == 0) {
#pragma unroll
                for (int ky = 0; ky < 5; ++ky) {
                    ap[ky*2+0] = aw[sy+ky][0];
                    ap[ky*2+1] = aw[sy+ky][1];
                }
                ap[10] = (aw[sy+0][2] & 0xFFFFu) | (aw[sy+1][2] << 16);
                ap[11] = (aw[sy+2][2] & 0xFFFFu) | (aw[sy+3][2] << 16);
                ap[12] =  aw[sy+4][2] & 0xFFFFu;
            } else {
#pragma unroll
                for (int ky = 0; ky < 5; ++ky) {
                    ap[ky*2+0] = (aw[sy+ky][0] >> 16) | (aw[sy+ky][1] << 16);
                    ap[ky*2+1] = (aw[sy+ky][1] >> 16) | (aw[sy+ky][2] << 16);
                }
                ap[10] = (aw[sy+0][2] >> 16) | (aw[sy+1][2] & 0xFFFF0000u);
                ap[11] = (aw[sy+2][2] >> 16) | (aw[sy+3][2] & 0xFFFF0000u);
                ap[12] =  aw[sy+4][2] >> 16;
            }

#pragma unroll
            for (int cl = 0; cl < 8; ++cl) {
                const unsigned* wr = sw + (c0 + cl)*13;
                int p = 0;
#pragma unroll
                for (int j = 0; j < 13; ++j)
                    p += __popc(ap[j] ^ wr[j]);
                int y = (int)kt[kbase + cl] - 2*p;
                s[cl] += y; q[cl] += y*y;
                mx[cl] = (y > mx[cl]) ? y : mx[cl];
                mn[cl] = (y < mn[cl]) ? y : mn[cl];
            }
        }

        {   // coalesced ext2 store: [t][32], 8 contiguous shorts = 16B
            s16x8 ev;
#pragma unroll
            for (int cl = 0; cl < 8; ++cl) {
                int co = c0 + cl;
                int sel = (selbs >> co) & 1;
                ev[cl] = (short)(sel ? mn[cl] : mx[cl]);
            }
            *(s16x8*)(ext2 + (size_t)t*32 + c0) = ev;
        }
    }

    // LDS-transpose stats reduction (writer 2-way bank-free with pad 67)
#pragma unroll
    for (int cl = 0; cl < 8; ++cl) {
        sqr[0][c0 + cl][pslot] = s[cl];
        sqr[1][c0 + cl][pslot] = q[cl];
    }
    __syncthreads();
    {
        int w = threadIdx.x;
        int typ = w >> 7, ch = (w >> 2) & 31, m = w & 3;
        int acc = 0;
#pragma unroll
        for (int k = 0; k < 16; ++k) acc += sqr[typ][ch][k*4 + m];
        slb[typ][ch][m] = acc;
    }
    __syncthreads();
    if (threadIdx.x < 64) {
        int typ = threadIdx.x >> 5, ch = threadIdx.x & 31;
        int tot = slb[typ][ch][0] + slb[typ][ch][1]
                + slb[typ][ch][2] + slb[typ][ch][3];
        partial2[(size_t)blockIdx.x*64 + typ*32 + ch] = tot;
    }
}

// finalize2 (int partials); thr on (y + bias) scale
__global__ __launch_bounds__(256) void k_finalize2i(const int* __restrict__ part,
                                                    int nblk,
                                                    const float* __restrict__ b2,
                                                    const float* __restrict__ g,
                                                    const float* __restrict__ be,
                                                    double* __restrict__ thr,
                                                    int* __restrict__ mode) {
    int c = blockIdx.x;
    long long s = 0, q = 0;
    for (int i = threadIdx.x; i < nblk; i += 256) {
        s += (long long)part[(size_t)i*64 + c];
        q += (long long)part[(size_t)i*64 + 32 + c];
    }
    __shared__ long long ls[256], lq[256];
    ls[threadIdx.x] = s; lq[threadIdx.x] = q;
    __syncthreads();
    for (int st = 128; st > 0; st >>= 1) {
        if (threadIdx.x < st) {
            ls[threadIdx.x] += ls[threadIdx.x + st];
            lq[threadIdx.x] += lq[threadIdx.x + st];
        }
        __syncthreads();
    }
    if (threadIdx.x == 0) {
        double N = (double)(BATCH * P1 * P1);
        double my = (double)ls[0] / N;
        double var = (double)lq[0] / N - my*my;   // bias-shift invariant
        double m = my + (double)b2[c];
        double gamma = (double)g[c], beta = (double)be[c];
        double sc = gamma / sqrt(var + 1e-5);
        int md; double tt = 0.0;
        if (sc > 0)      { md = 0; tt = m - beta / sc; }
        else if (sc < 0) { md = 1; tt = m - beta / sc; }
        else             { md = (beta >= 0) ? 2 : 3; }
        thr[c] = tt; mode[c] = md;
    }
}

// ---------------------------------------------------------------------------
// Fused stage-2 signs + FC; ext2 [t][32] -> vectorized contiguous reads.
// ---------------------------------------------------------------------------
__global__ __launch_bounds__(256) void k_sign2fc(const short* __restrict__ ext2,
                                                 const float* __restrict__ b2,
                                                 const double* __restrict__ thr,
                                                 const int* __restrict__ mode,
                                                 const unsigned* __restrict__ fcp,
                                                 const float* __restrict__ fcb,
                                                 float* __restrict__ out) {
    __shared__ char a2l[SF_IMGS*1568];
    __shared__ float sb[32];
    __shared__ double sthr[32];
    __shared__ int smd[32];
    if (threadIdx.x < 32) {
        sb[threadIdx.x]   = b2[threadIdx.x];
        sthr[threadIdx.x] = thr[threadIdx.x];
        smd[threadIdx.x]  = mode[threadIdx.x];
    }
    __syncthreads();

    const int b0 = blockIdx.x * SF_IMGS;
    for (int e = threadIdx.x; e < SF_IMGS*49; e += 256) {
        int il = e / 49, r = e % 49;
        int t = (b0 + il)*49 + r;
        const s16x8* ev = (const s16x8*)(ext2 + (size_t)t*32);
#pragma unroll 1
        for (int g = 0; g < 4; ++g) {
            s16x8 v8 = ev[g];
#pragma unroll
            for (int k = 0; k < 8; ++k) {
                int co = g*8 + k;
                float yf = (float)v8[k] + sb[co];
                int md = smd[co]; double tt = sthr[co];
                bool plus = (md == 0) ? ((double)yf >= tt)
                          : (md == 1) ? ((double)yf <= tt)
                          : (md == 2);
                a2l[il*1568 + co*49 + r] = plus ? (char)1 : (char)-1;
            }
        }
    }
    __syncthreads();

    for (int o = threadIdx.x; o < SF_IMGS*10; o += 256) {
        int il = o / 10, j = o % 10;
        const unsigned* ar = (const unsigned*)(a2l + il*1568);
        const unsigned* wr = fcp + j*392;
        int p = 0;
        for (int g = 0; g < 392; ++g)
            p += __popc((ar[g] ^ wr[g]) & 0x02020202u);
        out[(b0 + il)*10 + j] = (float)(1568 - 2*p) + fcb[j];
    }
}

// ---------------------------------------------------------------------------
extern "C" void kernel_launch(void* const* d_in, const int* in_sizes, int n_in,
                              void* d_out, int out_size, void* d_ws, size_t ws_size,
                              hipStream_t stream) {
    const float* x    = (const float*)d_in[0];
    const float* w1   = (const float*)d_in[1];
    const float* b1   = (const float*)d_in[2];
    const float* bn1g = (const float*)d_in[3];
    const float* bn1b = (const float*)d_in[4];
    const float* w2   = (const float*)d_in[5];
    const float* b2   = (const float*)d_in[6];
    const float* bn2g = (const float*)d_in[7];
    const float* bn2b = (const float*)d_in[8];
    const float* fcw  = (const float*)d_in[9];
    const float* fcb  = (const float*)d_in[10];
    float* out = (float*)d_out;

    char* ws = (char*)d_ws;
    size_t cur = 0;
    auto alloc = [&](size_t sz) {
        size_t o = cur;
        cur += (sz + 255) & ~(size_t)255;
        return o;
    };
    unsigned*       w1s      = (unsigned*)(ws + alloc(16 * 4));
    unsigned*       w2p      = (unsigned*)(ws + alloc(416 * 4));
    unsigned short* w2k      = (unsigned short*)(ws + alloc(800 * 2));
    unsigned*       fcp      = (unsigned*)(ws + alloc(3920 * 4));
    unsigned*       selb     = (unsigned*)(ws + alloc(2 * 4));
    double*         thr1     = (double*)(ws + alloc(16 * 8));
    int*            mode1    = (int*)(ws + alloc(16 * 4));
    double*         thr2     = (double*)(ws + alloc(32 * 8));
    int*            mode2    = (int*)(ws + alloc(32 * 4));
    double*         partial1 = (double*)(ws + alloc((size_t)QD_BLOCKS * 32 * 8));
    int*            partial2 = (int*)(ws + alloc((size_t)C2F_BLOCKS * 64 * 4));
    unsigned short* a1b      = (unsigned short*)(ws + alloc((size_t)NPOOL1 * 2));
    // ext1 (f32, 102.8 MB) and ext2 (s16, 25.7 MB): disjoint lifetimes -> share
    size_t extoff = alloc((size_t)C1 * NPOOL1 * 4);
    float* ext1 = (float*)(ws + extoff);
    short* ext2 = (short*)(ws + extoff);

    k_prep<<<13, 256, 0, stream>>>(w1, w2, fcw, bn1g, bn2g,
                                   w1s, w2p, w2k, fcp, selb);
    k_conv1_quad<<<QD_BLOCKS, 256, 0, stream>>>(x, w1s, b1, selb, ext1, partial1);
    k_finalize1<<<16, 256, 0, stream>>>(partial1, QD_BLOCKS, bn1g, bn1b, thr1, mode1);
    k_sign1<<<S1_BLOCKS, 256, 0, stream>>>(ext1, thr1, mode1, a1b);
    k_conv2_fused<<<C2F_BLOCKS, 256, 0, stream>>>(a1b, w2p, w2k, selb, ext2, partial2);
    k_finalize2i<<<32, 256, 0, stream>>>(partial2, C2F_BLOCKS, b2, bn2g, bn2b, thr2, mode2);
    k_sign2fc<<<SF_BLOCKS, 256, 0, stream>>>(ext2, b2, thr2, mode2, fcp, fcb, out);
}

// Round 21
// 222.560 us; speedup vs baseline: 1.1505x; 1.1505x over previous
//
#include <hip/hip_runtime.h>
#include <stdint.h>

#define BATCH 8192
#define H1 28
#define W1 28
#define C1 16
#define P1 14
#define C2 32
#define P2 7

#define NPIX1  (BATCH*H1*W1)    // 6,422,528
#define NPOOL1 (BATCH*P1*P1)    // 1,605,632
#define NPOOL2 (BATCH*P2*P2)    // 401,408

#define QD_BLOCKS 3136          // 401,408 quads, 128/block (2 wave-pairs)
#define S1_BLOCKS 1568          // sign1: NPOOL1/(256*4)
#define C2F_BLOCKS 6272         // conv2 v2: 64 positions/block, quarter split
#define SF_IMGS   16
#define SF_BLOCKS 512           // BATCH/SF_IMGS

typedef float f32x2 __attribute__((ext_vector_type(2)));
typedef float f32x4 __attribute__((ext_vector_type(4)));
typedef short s16x4 __attribute__((ext_vector_type(4)));
typedef short s16x8 __attribute__((ext_vector_type(8)));

// ---------------------------------------------------------------------------
// Weight prep, parallelized across 13 blocks (round-15 proven).
// ---------------------------------------------------------------------------
__global__ __launch_bounds__(256) void k_prep(const float* __restrict__ w1,
                                              const float* __restrict__ w2,
                                              const float* __restrict__ fcw,
                                              const float* __restrict__ g1,
                                              const float* __restrict__ g2,
                                              unsigned* __restrict__ w1s,
                                              unsigned* __restrict__ w2p,
                                              unsigned short* __restrict__ w2k,
                                              unsigned* __restrict__ fcp,
                                              unsigned* __restrict__ selb) {
    const int blk = blockIdx.x;
    if (blk == 0) {
        for (int c = threadIdx.x; c < 16; c += 256) {
            unsigned sb = 0;
            for (int i = 0; i < 25; ++i)
                if (w1[c*25 + i] < 0.f) sb |= 1u << i;
            w1s[c] = sb;
        }
        if (threadIdx.x == 0) {
            unsigned s1 = 0, s2 = 0;
            for (int c = 0; c < 16; ++c) if (g1[c] < 0.f) s1 |= 1u << c;
            for (int c = 0; c < 32; ++c) if (g2[c] < 0.f) s2 |= 1u << c;
            selb[0] = s1; selb[1] = s2;
        }
    } else if (blk == 1) {
        for (int i = threadIdx.x; i < 32*13; i += 256) {
            int co = i / 13, j = i % 13;
            int k1, k2;
            if (j < 10)      { k1 = (j/2)*5 + (j&1)*2; k2 = k1 + 1; }
            else if (j == 10){ k1 = 4;  k2 = 9;  }
            else if (j == 11){ k1 = 14; k2 = 19; }
            else             { k1 = 24; k2 = -1; }
            unsigned lo = 0, hi = 0;
            for (int ci = 0; ci < 16; ++ci) {
                if (w2[co*400 + ci*25 + k1] >= 0.f) lo |= 1u << ci;
                if (k2 >= 0 && w2[co*400 + ci*25 + k2] >= 0.f) hi |= 1u << ci;
            }
            w2p[i] = lo | (hi << 16);
        }
    } else if (blk == 2) {
        __shared__ unsigned short sw2b[800];
        for (int i = threadIdx.x; i < 800; i += 256) {
            int co = i / 25, kk = i % 25;
            unsigned m = 0;
            for (int ci = 0; ci < 16; ++ci)
                if (w2[co*400 + ci*25 + kk] >= 0.f) m |= 1u << ci;
            sw2b[i] = (unsigned short)m;
        }
        __syncthreads();
        const int lo5[5] = {2,1,0,0,0};
        const int hi5[5] = {4,4,4,3,2};
        for (int i = threadIdx.x; i < 800; i += 256) {
            int cls = i >> 5, co = i & 31;
            int rc = cls / 5, cc = cls % 5;
            int rlo = lo5[rc], rhi = hi5[rc], clo = lo5[cc], chi = hi5[cc];
            int C = 0;
            for (int ky = 0; ky < 5; ++ky)
                for (int kx = 0; kx < 5; ++kx)
                    if (ky < rlo || ky > rhi || kx < clo || kx > chi)
                        C += __popc((unsigned)sw2b[co*25 + ky*5 + kx]);
            int nv = (rhi - rlo + 1) * (chi - clo + 1);
            w2k[i] = (unsigned short)(16*nv + 2*C);
        }
    } else {
        int i0 = (blk - 3) * 392;
        for (int ii = threadIdx.x; ii < 392; ii += 256) {
            int i = i0 + ii;
            int j = i / 392, g = i % 392;
            unsigned v = 0;
            for (int by = 0; by < 4; ++by) {
                int k = g*4 + by;
                unsigned char s = (fcw[j*1568 + k] >= 0.f) ? 0x01 : 0xFF;
                v |= ((unsigned)s) << (8*by);
            }
            fcp[i] = v;
        }
    }
}

// ---------------------------------------------------------------------------
// conv1 QUAD (round-18 proven: ~77us, VGPR 84, no spill). Conflict-free
// LDS-transpose stats reduction (sqred pad 136).
// ---------------------------------------------------------------------------
__global__ __launch_bounds__(256) void k_conv1_quad(const float* __restrict__ x,
                                                    const unsigned* __restrict__ w1s,
                                                    const float* __restrict__ b1,
                                                    const unsigned* __restrict__ selb,
                                                    float* __restrict__ ext1,
                                                    double* __restrict__ partial1) {
    const int wave = threadIdx.x >> 6, lane = threadIdx.x & 63;
    const int half = wave & 1;
    const int pg   = wave >> 1;
    const int c0   = half << 3;
    const int elem = pg*64 + lane;      // 0..127 slot within channel-half
    unsigned selbs = __builtin_amdgcn_readfirstlane(selb[0]);

    __shared__ float sqred[2][16][136]; // pad 136 -> conflict-free both phases
    __shared__ float slb[2][16][8];

    float bv[8];
#pragma unroll
    for (int cl = 0; cl < 8; ++cl) bv[cl] = b1[c0 + cl];

    const int qq = blockIdx.x*128 + pg*64 + lane;
    const int b  = qq / 49;
    const int rr = qq % 49;
    const int qy = rr / 7, qx = rr % 7;
    const float* xb = x + (size_t)b * (H1*W1);

    const int ix0 = 4*qx - 2;
    const bool cL = (qx == 0), cR = (qx == 6);
    const int o0 = cL ? 0 : ix0;
    const int o3 = cR ? 24 : ix0 + 6;

    float xd[64];
#pragma unroll
    for (int dy = 0; dy < 8; ++dy) {
        int iy = 4*qy + dy - 2;
        bool rv = (iy >= 0) && (iy < H1);
        const float* rp = xb + (rv ? iy : 0)*W1;
        f32x2 p0 = *(const f32x2*)(rp + o0);
        f32x2 p1 = *(const f32x2*)(rp + ix0 + 2);
        f32x2 p2 = *(const f32x2*)(rp + ix0 + 4);
        f32x2 p3 = *(const f32x2*)(rp + o3);
        bool vL = rv && !cL, vR = rv && !cR;
        xd[dy*8+0] = vL ? p0.x : 0.f;
        xd[dy*8+1] = vL ? p0.y : 0.f;
        xd[dy*8+2] = rv ? p1.x : 0.f;
        xd[dy*8+3] = rv ? p1.y : 0.f;
        xd[dy*8+4] = rv ? p2.x : 0.f;
        xd[dy*8+5] = rv ? p2.y : 0.f;
        xd[dy*8+6] = vR ? p3.x : 0.f;
        xd[dy*8+7] = vR ? p3.y : 0.f;
    }

#pragma unroll
    for (int cl = 0; cl < 8; ++cl) {
        unsigned sb = __builtin_amdgcn_readfirstlane(w1s[c0 + cl]);
        f32x2 y00={0.f,0.f}, y01={0.f,0.f}, y10={0.f,0.f}, y11={0.f,0.f};
        f32x2 y20={0.f,0.f}, y21={0.f,0.f}, y30={0.f,0.f}, y31={0.f,0.f};
#pragma unroll
        for (int ky = 0; ky < 5; ++ky) {
#pragma unroll
            for (int kx = 0; kx < 5; ++kx) {
                float m = __uint_as_float(0x3F800000u ^
                            (((sb >> (ky*5 + kx)) & 1u) << 31));
                f32x2 mm = {m, m};
                f32x2 a0 = { xd[(0+ky)*8 + kx    ], xd[(0+ky)*8 + kx + 1] };
                f32x2 a1 = { xd[(0+ky)*8 + kx + 2], xd[(0+ky)*8 + kx + 3] };
                f32x2 b0 = { xd[(1+ky)*8 + kx    ], xd[(1+ky)*8 + kx + 1] };
                f32x2 b1v= { xd[(1+ky)*8 + kx + 2], xd[(1+ky)*8 + kx + 3] };
                f32x2 c0v= { xd[(2+ky)*8 + kx    ], xd[(2+ky)*8 + kx + 1] };
                f32x2 c1 = { xd[(2+ky)*8 + kx + 2], xd[(2+ky)*8 + kx + 3] };
                f32x2 d0 = { xd[(3+ky)*8 + kx    ], xd[(3+ky)*8 + kx + 1] };
                f32x2 d1 = { xd[(3+ky)*8 + kx + 2], xd[(3+ky)*8 + kx + 3] };
                y00 = a0*mm + y00;  y01 = a1*mm + y01;   // exact ±x adds
                y10 = b0*mm + y10;  y11 = b1v*mm + y11;
                y20 = c0v*mm + y20; y21 = c1*mm + y21;
                y30 = d0*mm + y30;  y31 = d1*mm + y31;
            }
        }
        float bb = bv[cl];
        f32x2 bb2 = {bb, bb};
        y00 += bb2; y01 += bb2; y10 += bb2; y11 += bb2;
        y20 += bb2; y21 += bb2; y30 += bb2; y31 += bb2;

        int c = c0 + cl;
        int sel = (selbs >> c) & 1;
        float e00 = sel ? fminf(fminf(y00.x,y00.y), fminf(y10.x,y10.y))
                        : fmaxf(fmaxf(y00.x,y00.y), fmaxf(y10.x,y10.y));
        float e01 = sel ? fminf(fminf(y01.x,y01.y), fminf(y11.x,y11.y))
                        : fmaxf(fmaxf(y01.x,y01.y), fmaxf(y11.x,y11.y));
        float e10 = sel ? fminf(fminf(y20.x,y20.y), fminf(y30.x,y30.y))
                        : fmaxf(fmaxf(y20.x,y20.y), fmaxf(y30.x,y30.y));
        float e11 = sel ? fminf(fminf(y21.x,y21.y), fminf(y31.x,y31.y))
                        : fmaxf(fmaxf(y21.x,y21.y), fmaxf(y31.x,y31.y));
        size_t base = (size_t)c*NPOOL1 + (size_t)b*(P1*P1) + (2*qy)*P1 + 2*qx;
        f32x2 ev0 = {e00, e01};
        f32x2 ev1 = {e10, e11};
        *(f32x2*)(ext1 + base)      = ev0;
        *(f32x2*)(ext1 + base + P1) = ev1;

        f32x2 sp = ((y00 + y01) + (y10 + y11)) + ((y20 + y21) + (y30 + y31));
        f32x2 qp = y00*y00;
        qp = y01*y01 + qp; qp = y10*y10 + qp; qp = y11*y11 + qp;
        qp = y20*y20 + qp; qp = y21*y21 + qp; qp = y30*y30 + qp;
        qp = y31*y31 + qp;
        sqred[0][c][elem] = sp.x + sp.y;
        sqred[1][c][elem] = qp.x + qp.y;
    }

    __syncthreads();
    {
        int w = threadIdx.x;
        int c = w >> 4, sub = w & 15, typ = sub >> 3, m = sub & 7;
        float acc = 0.f;
#pragma unroll
        for (int k = 0; k < 16; ++k) acc += sqred[typ][c][k*8 + m];
        slb[typ][c][m] = acc;
    }
    __syncthreads();
    if (threadIdx.x < 32) {
        int c = threadIdx.x & 15, typ = threadIdx.x >> 4;
        double d = 0.0;
#pragma unroll
        for (int j = 0; j < 8; ++j) d += (double)slb[typ][c][j];
        partial1[(size_t)blockIdx.x*32 + typ*16 + c] = d;
    }
}

// finalize1: reduce partials, per-channel threshold + mode
__global__ __launch_bounds__(256) void k_finalize1(const double* __restrict__ part,
                                                   int nblk,
                                                   const float* __restrict__ g,
                                                   const float* __restrict__ be,
                                                   double* __restrict__ thr,
                                                   int* __restrict__ mode) {
    int c = blockIdx.x;
    double s = 0, q = 0;
    for (int i = threadIdx.x; i < nblk; i += 256) {
        s += part[(size_t)i*32 + c];
        q += part[(size_t)i*32 + 16 + c];
    }
    __shared__ double ls[256], lq[256];
    ls[threadIdx.x] = s; lq[threadIdx.x] = q;
    __syncthreads();
    for (int st = 128; st > 0; st >>= 1) {
        if (threadIdx.x < st) {
            ls[threadIdx.x] += ls[threadIdx.x + st];
            lq[threadIdx.x] += lq[threadIdx.x + st];
        }
        __syncthreads();
    }
    if (threadIdx.x == 0) {
        double N = (double)NPIX1;
        double m = ls[0] / N;
        double var = lq[0] / N - m*m;
        double gamma = (double)g[c], beta = (double)be[c];
        double sc = gamma / sqrt(var + 1e-5);
        int md; double tt = 0.0;
        if (sc > 0)      { md = 0; tt = m - beta / sc; }
        else if (sc < 0) { md = 1; tt = m - beta / sc; }
        else             { md = (beta >= 0) ? 2 : 3; }
        thr[c] = tt; mode[c] = md;
    }
}

// sign1 x4 (round-19): 4 positions/thread, vectorized loads/stores.
__global__ __launch_bounds__(256) void k_sign1(const float* __restrict__ ext1,
                                               const double* __restrict__ thr,
                                               const int* __restrict__ mode,
                                               unsigned short* __restrict__ a1b) {
    int t0 = (blockIdx.x*256 + threadIdx.x) * 4;
    unsigned bits0 = 0, bits1 = 0, bits2 = 0, bits3 = 0;
#pragma unroll
    for (int c = 0; c < 16; ++c) {
        f32x4 v = *(const f32x4*)(ext1 + (size_t)c*NPOOL1 + t0);
        int md = mode[c]; double tt = thr[c];
        bool p0, p1, p2, p3;
        if (md == 0) {
            p0 = ((double)v.x >= tt); p1 = ((double)v.y >= tt);
            p2 = ((double)v.z >= tt); p3 = ((double)v.w >= tt);
        } else if (md == 1) {
            p0 = ((double)v.x <= tt); p1 = ((double)v.y <= tt);
            p2 = ((double)v.z <= tt); p3 = ((double)v.w <= tt);
        } else {
            bool pv = (md == 2);
            p0 = pv; p1 = pv; p2 = pv; p3 = pv;
        }
        bits0 |= (p0 ? 1u : 0u) << c;
        bits1 |= (p1 ? 1u : 0u) << c;
        bits2 |= (p2 ? 1u : 0u) << c;
        bits3 |= (p3 ? 1u : 0u) << c;
    }
    s16x4 outv = { (short)bits0, (short)bits1, (short)bits2, (short)bits3 };
    *(s16x4*)(a1b + t0) = outv;
}

// ---------------------------------------------------------------------------
// conv2 fused v2 (round-16/18 proven: ~75us, VGPR 84, occ 28%): LDS
// word-reads, funnel-shift packing, coalesced ext2 [t][32], quarter split.
// ---------------------------------------------------------------------------
__global__ __launch_bounds__(256) void k_conv2_fused(const unsigned short* __restrict__ a1b,
                                                     const unsigned* __restrict__ w2p,
                                                     const unsigned short* __restrict__ w2k,
                                                     const unsigned* __restrict__ selb,
                                                     short* __restrict__ ext2,
                                                     int* __restrict__ partial2) {
    __shared__ unsigned short raw[3*18*18];
    __shared__ unsigned sw[32*13];
    __shared__ unsigned short kt[25*32];
    __shared__ int lsum[4][32], lsq[4][32];

    const int B0 = blockIdx.x * 64;
    const int i0 = B0 / 49;
    const int ilast = (B0 + 63) / 49;
    const int icnt = ilast - i0 + 1;       // 2 or 3

    for (int i = threadIdx.x; i < 416; i += 256) sw[i] = w2p[i];
    for (int i = threadIdx.x; i < 800; i += 256) kt[i] = w2k[i];
    {
        unsigned* rz = (unsigned*)raw;
        int n32 = icnt * 162;
        for (int i = threadIdx.x; i < n32; i += 256) rz[i] = 0u;
    }
    __syncthreads();
    {
        int n = icnt * 196;
        for (int e = threadIdx.x; e < n; e += 256) {
            int img = e / 196, lin = e % 196;
            unsigned short v = a1b[(size_t)(i0 + img)*196 + lin];
            int py = lin / 14, px = lin % 14;
            raw[(img*18 + py + 2)*18 + px + 2] = v;
        }
    }
    __syncthreads();

    const int quarter = threadIdx.x & 3;
    const int c0 = quarter << 3;
    const int t = B0 + (threadIdx.x >> 2);
    const int img = t / 49 - i0;
    const int r = t % 49;
    const int qy = r / 7, qx = r % 7;
    const unsigned selbs = __builtin_amdgcn_readfirstlane(selb[1]);

    const unsigned* raw32 = (const unsigned*)raw;
    unsigned aw[6][3];
#pragma unroll
    for (int wy = 0; wy < 6; ++wy) {
        int base16 = (img*18 + 2*qy + wy)*18 + 2*qx;   // even
        int wbase = base16 >> 1;
        aw[wy][0] = raw32[wbase + 0];
        aw[wy][1] = raw32[wbase + 1];
        aw[wy][2] = raw32[wbase + 2];
    }

    int s[8], q[8], mx[8], mn[8];
#pragma unroll
    for (int i = 0; i < 8; ++i) { s[i]=0; q[i]=0; mx[i]=-1000000; mn[i]=1000000; }

#pragma unroll
    for (int sp = 0; sp < 4; ++sp) {
        const int sy = sp >> 1, sx = sp & 1;
        const int oy = 2*qy + sy, ox = 2*qx + sx;
        const int rcls = (oy < 2) ? oy : ((oy > 11) ? oy - 9 : 2);
        const int ccls = (ox < 2) ? ox : ((ox > 11) ? ox - 9 : 2);
        const int kbase = (rcls*5 + ccls) * 32 + c0;

        unsigned ap[13];
        if (sx == 0) {
#pragma unroll
            for (int ky = 0; ky < 5; ++ky) {
                ap[ky*2+0] = aw[sy+ky][0];
                ap[ky*2+1] = aw[sy+ky][1];
            }
            ap[10] = (aw[sy+0][2] & 0xFFFFu) | (aw[sy+1][2] << 16);
            ap[11] = (aw[sy+2][2] & 0xFFFFu) | (aw[sy+3][2] << 16);
            ap[12] =  aw[sy+4][2] & 0xFFFFu;
        } else {
#pragma unroll
            for (int ky = 0; ky < 5; ++ky) {
                ap[ky*2+0] = (aw[sy+ky][0] >> 16) | (aw[sy+ky][1] << 16);
                ap[ky*2+1] = (aw[sy+ky][1] >> 16) | (aw[sy+ky][2] << 16);
            }
            ap[10] = (aw[sy+0][2] >> 16) | (aw[sy+1][2] & 0xFFFF0000u);
            ap[11] = (aw[sy+2][2] >> 16) | (aw[sy+3][2] & 0xFFFF0000u);
            ap[12] =  aw[sy+4][2] >> 16;
        }

#pragma unroll
        for (int cl = 0; cl < 8; ++cl) {
            const unsigned* wr = sw + (c0 + cl)*13;
            int p = 0;
#pragma unroll
            for (int j = 0; j < 13; ++j)
                p += __popc(ap[j] ^ wr[j]);
            int y = (int)kt[kbase + cl] - 2*p;
            s[cl] += y; q[cl] += y*y;
            mx[cl] = (y > mx[cl]) ? y : mx[cl];
            mn[cl] = (y < mn[cl]) ? y : mn[cl];
        }
    }

    {   // coalesced ext2 store: [t][32] layout, 8 contiguous shorts = 16B
        s16x8 ev;
#pragma unroll
        for (int cl = 0; cl < 8; ++cl) {
            int co = c0 + cl;
            int sel = (selbs >> co) & 1;
            ev[cl] = (short)(sel ? mn[cl] : mx[cl]);
        }
        *(s16x8*)(ext2 + (size_t)t*32 + c0) = ev;
    }

    int wave = threadIdx.x >> 6, lane = threadIdx.x & 63;
#pragma unroll
    for (int cl = 0; cl < 8; ++cl) {
        int ss = s[cl], qq = q[cl];
#pragma unroll
        for (int off = 32; off >= 4; off >>= 1) {   // quarter-preserving
            ss += __shfl_down(ss, off);
            qq += __shfl_down(qq, off);
        }
        if (lane < 4) {
            lsum[wave][lane*8 + cl] = ss;
            lsq[wave][lane*8 + cl]  = qq;
        }
    }
    __syncthreads();
    if (threadIdx.x < 32) {
        int co = threadIdx.x;
        partial2[(size_t)blockIdx.x*64 + co] =
            lsum[0][co] + lsum[1][co] + lsum[2][co] + lsum[3][co];
    } else if (threadIdx.x < 64) {
        int co = threadIdx.x - 32;
        partial2[(size_t)blockIdx.x*64 + 32 + co] =
            lsq[0][co] + lsq[1][co] + lsq[2][co] + lsq[3][co];
    }
}

// finalize2 (int partials); thr on (y + bias) scale
__global__ __launch_bounds__(256) void k_finalize2i(const int* __restrict__ part,
                                                    int nblk,
                                                    const float* __restrict__ b2,
                                                    const float* __restrict__ g,
                                                    const float* __restrict__ be,
                                                    double* __restrict__ thr,
                                                    int* __restrict__ mode) {
    int c = blockIdx.x;
    long long s = 0, q = 0;
    for (int i = threadIdx.x; i < nblk; i += 256) {
        s += (long long)part[(size_t)i*64 + c];
        q += (long long)part[(size_t)i*64 + 32 + c];
    }
    __shared__ long long ls[256], lq[256];
    ls[threadIdx.x] = s; lq[threadIdx.x] = q;
    __syncthreads();
    for (int st = 128; st > 0; st >>= 1) {
        if (threadIdx.x < st) {
            ls[threadIdx.x] += ls[threadIdx.x + st];
            lq[threadIdx.x] += lq[threadIdx.x + st];
        }
        __syncthreads();
    }
    if (threadIdx.x == 0) {
        double N = (double)(BATCH * P1 * P1);
        double my = (double)ls[0] / N;
        double var = (double)lq[0] / N - my*my;   // bias-shift invariant
        double m = my + (double)b2[c];
        double gamma = (double)g[c], beta = (double)be[c];
        double sc = gamma / sqrt(var + 1e-5);
        int md; double tt = 0.0;
        if (sc > 0)      { md = 0; tt = m - beta / sc; }
        else if (sc < 0) { md = 1; tt = m - beta / sc; }
        else             { md = (beta >= 0) ? 2 : 3; }
        thr[c] = tt; mode[c] = md;
    }
}

// ---------------------------------------------------------------------------
// Fused stage-2 signs + FC; ext2 [t][32] -> vectorized contiguous reads.
// ---------------------------------------------------------------------------
__global__ __launch_bounds__(256) void k_sign2fc(const short* __restrict__ ext2,
                                                 const float* __restrict__ b2,
                                                 const double* __restrict__ thr,
                                                 const int* __restrict__ mode,
                                                 const unsigned* __restrict__ fcp,
                                                 const float* __restrict__ fcb,
                                                 float* __restrict__ out) {
    __shared__ char a2l[SF_IMGS*1568];
    __shared__ float sb[32];
    __shared__ double sthr[32];
    __shared__ int smd[32];
    if (threadIdx.x < 32) {
        sb[threadIdx.x]   = b2[threadIdx.x];
        sthr[threadIdx.x] = thr[threadIdx.x];
        smd[threadIdx.x]  = mode[threadIdx.x];
    }
    __syncthreads();

    const int b0 = blockIdx.x * SF_IMGS;
    for (int e = threadIdx.x; e < SF_IMGS*49; e += 256) {
        int il = e / 49, r = e % 49;
        int t = (b0 + il)*49 + r;
        const s16x8* ev = (const s16x8*)(ext2 + (size_t)t*32);
#pragma unroll 1
        for (int g = 0; g < 4; ++g) {
            s16x8 v8 = ev[g];
#pragma unroll
            for (int k = 0; k < 8; ++k) {
                int co = g*8 + k;
                float yf = (float)v8[k] + sb[co];
                int md = smd[co]; double tt = sthr[co];
                bool plus = (md == 0) ? ((double)yf >= tt)
                          : (md == 1) ? ((double)yf <= tt)
                          : (md == 2);
                a2l[il*1568 + co*49 + r] = plus ? (char)1 : (char)-1;
            }
        }
    }
    __syncthreads();

    for (int o = threadIdx.x; o < SF_IMGS*10; o += 256) {
        int il = o / 10, j = o % 10;
        const unsigned* ar = (const unsigned*)(a2l + il*1568);
        const unsigned* wr = fcp + j*392;
        int p = 0;
        for (int g = 0; g < 392; ++g)
            p += __popc((ar[g] ^ wr[g]) & 0x02020202u);
        out[(b0 + il)*10 + j] = (float)(1568 - 2*p) + fcb[j];
    }
}

// ---------------------------------------------------------------------------
extern "C" void kernel_launch(void* const* d_in, const int* in_sizes, int n_in,
                              void* d_out, int out_size, void* d_ws, size_t ws_size,
                              hipStream_t stream) {
    const float* x    = (const float*)d_in[0];
    const float* w1   = (const float*)d_in[1];
    const float* b1   = (const float*)d_in[2];
    const float* bn1g = (const float*)d_in[3];
    const float* bn1b = (const float*)d_in[4];
    const float* w2   = (const float*)d_in[5];
    const float* b2   = (const float*)d_in[6];
    const float* bn2g = (const float*)d_in[7];
    const float* bn2b = (const float*)d_in[8];
    const float* fcw  = (const float*)d_in[9];
    const float* fcb  = (const float*)d_in[10];
    float* out = (float*)d_out;

    char* ws = (char*)d_ws;
    size_t cur = 0;
    auto alloc = [&](size_t sz) {
        size_t o = cur;
        cur += (sz + 255) & ~(size_t)255;
        return o;
    };
    unsigned*       w1s      = (unsigned*)(ws + alloc(16 * 4));
    unsigned*       w2p      = (unsigned*)(ws + alloc(416 * 4));
    unsigned short* w2k      = (unsigned short*)(ws + alloc(800 * 2));
    unsigned*       fcp      = (unsigned*)(ws + alloc(3920 * 4));
    unsigned*       selb     = (unsigned*)(ws + alloc(2 * 4));
    double*         thr1     = (double*)(ws + alloc(16 * 8));
    int*            mode1    = (int*)(ws + alloc(16 * 4));
    double*         thr2     = (double*)(ws + alloc(32 * 8));
    int*            mode2    = (int*)(ws + alloc(32 * 4));
    double*         partial1 = (double*)(ws + alloc((size_t)QD_BLOCKS * 32 * 8));
    int*            partial2 = (int*)(ws + alloc((size_t)C2F_BLOCKS * 64 * 4));
    unsigned short* a1b      = (unsigned short*)(ws + alloc((size_t)NPOOL1 * 2));
    // ext1 (f32, 102.8 MB) and ext2 (s16, 25.7 MB): disjoint lifetimes -> share
    size_t extoff = alloc((size_t)C1 * NPOOL1 * 4);
    float* ext1 = (float*)(ws + extoff);
    short* ext2 = (short*)(ws + extoff);

    k_prep<<<13, 256, 0, stream>>>(w1, w2, fcw, bn1g, bn2g,
                                   w1s, w2p, w2k, fcp, selb);
    k_conv1_quad<<<QD_BLOCKS, 256, 0, stream>>>(x, w1s, b1, selb, ext1, partial1);
    k_finalize1<<<16, 256, 0, stream>>>(partial1, QD_BLOCKS, bn1g, bn1b, thr1, mode1);
    k_sign1<<<S1_BLOCKS, 256, 0, stream>>>(ext1, thr1, mode1, a1b);
    k_conv2_fused<<<C2F_BLOCKS, 256, 0, stream>>>(a1b, w2p, w2k, selb, ext2, partial2);
    k_finalize2i<<<32, 256, 0, stream>>>(partial2, C2F_BLOCKS, b2, bn2g, bn2b, thr2, mode2);
    k_sign2fc<<<SF_BLOCKS, 256, 0, stream>>>(ext2, b2, thr2, mode2, fcp, fcb, out);
}